// Round 3
// baseline (379.814 us; speedup 1.0000x reference)
//
#include <hip/hip_runtime.h>
#include <stdint.h>

// Pipeline (all MFMA inputs bf16, accum f32):
//  k0 : W_v,W_g,W_o,W_b -> bf16 (Wvg[512][64], Wo[64][256], Wb[16][128])
//  k1 : wbuf[h][i][j] = softmax_j( LN(z[i,j,:]).Wb[h,:] + INF*(zmask-1) )  (fused, bf16)
//  k2 : vT[h][s*32+c][j] = (LN(m[s,j,:]).Wv[hc,:])*mask[s,j]   (bf16, direct stores)
//       gbuf[s][i][hc]   = sigmoid(LN(m[s,i,:]).Wg[hc,:])      (bf16, LDS-transposed)
//  k3 : O2[i][s][hc] = sum_j wbuf[h][i][j]*vT[h][s*32+c][j]    (bf16, XCD-swizzled)
//  k4 : out[s][i][cm] = sum_hc (gbuf*O2)[s,i,hc] * Wo[cm][hc]  (f32)

typedef unsigned short u16;
typedef unsigned int u32;
typedef __attribute__((ext_vector_type(4))) float f32x4;
typedef __attribute__((ext_vector_type(8))) short bf16x8;

__device__ __forceinline__ u16 f2bf(float f) {
  u32 u = __float_as_uint(f);
  u = u + 0x7fffu + ((u >> 16) & 1u);
  return (u16)(u >> 16);
}
__device__ __forceinline__ float bf2f(u16 h) { return __uint_as_float(((u32)h) << 16); }

__device__ __forceinline__ bf16x8 pack8(const float* f) {
  bf16x8 r;
#pragma unroll
  for (int e = 0; e < 8; ++e) r[e] = (short)f2bf(f[e]);
  return r;
}

#define GLD_LDS16(gp, lp) __builtin_amdgcn_global_load_lds(                 \
    (__attribute__((address_space(1))) const void*)(gp),                    \
    (__attribute__((address_space(3))) void*)(lp), 16, 0, 0)

// ---------------------------------------------------------------- k0
__global__ __launch_bounds__(256) void k0_convert(
    const float* __restrict__ W_v, const float* __restrict__ W_g,
    const float* __restrict__ W_o, const float* __restrict__ W_b,
    u16* __restrict__ Wvg, u16* __restrict__ Wo, u16* __restrict__ Wb)
{
  int id = blockIdx.x * 256 + threadIdx.x;
  if (id < 32768) {
    int row = id >> 6, col = id & 63;
    float v = (row < 256) ? W_v[row * 64 + col] : W_g[(row - 256) * 64 + col];
    Wvg[id] = f2bf(v);
  } else if (id < 49152) {
    int k = id - 32768;
    Wo[k] = f2bf(W_o[k]);
  } else if (id < 51200) {
    int k = id - 49152;
    Wb[k] = (k < 1024) ? f2bf(W_b[k]) : (u16)0;
  }
}

// ---------------------------------------------------------------- k1 (fused bias+softmax)
// grid 512 (one per i). block 256 = 4 waves.
__global__ __launch_bounds__(256) void k1_fused(
    const float* __restrict__ z, const float* __restrict__ z_mask,
    const float* __restrict__ gzp, const float* __restrict__ bzp,
    const u16* __restrict__ Wb, u16* __restrict__ wbuf)
{
  const int i = blockIdx.x;
  const int t = threadIdx.x, lane = t & 63, wid = t >> 6;
  const int r16 = lane & 15, kg = lane >> 4;
  __shared__ char zns[32768];            // zn[128 rows][256B] bf16, XOR(row&7) swizzled
  __shared__ float bbl[8][520];          // bias rows per head
  __shared__ float gz[128], bz[128];
  if (t < 128) { gz[t] = gzp[t]; bz[t] = bzp[t]; }
  // Wb fragments (rows 8..15 are zero-padded)
  bf16x8 bw[4];
#pragma unroll
  for (int kf = 0; kf < 4; ++kf)
    bw[kf] = *reinterpret_cast<const bf16x8*>(Wb + r16 * 128 + kf * 32 + kg * 8);
  __syncthreads();

  for (int jc = 0; jc < 4; ++jc) {
    const int j0 = jc * 128;
    // LayerNorm: 2 passes, 4 threads per 128-f32 row
#pragma unroll
    for (int rr = 0; rr < 2; ++rr) {
      const int row = rr * 64 + (t >> 2), part = t & 3;
      const float* zr = z + ((size_t)i * 512 + j0 + row) * 128 + part * 32;
      f32x4 v[8];
      float s = 0.f, sq = 0.f;
#pragma unroll
      for (int q = 0; q < 8; ++q) {
        v[q] = *reinterpret_cast<const f32x4*>(zr + 4 * q);
#pragma unroll
        for (int e = 0; e < 4; ++e) { s += v[q][e]; sq += v[q][e] * v[q][e]; }
      }
      s += __shfl_xor(s, 1); s += __shfl_xor(s, 2);
      sq += __shfl_xor(sq, 1); sq += __shfl_xor(sq, 2);
      float mean = s * (1.f / 128.f);
      float rstd = rsqrtf(sq * (1.f / 128.f) - mean * mean + 1e-5f);
#pragma unroll
      for (int uu = 0; uu < 4; ++uu) {
        float tmp[8];
#pragma unroll
        for (int e = 0; e < 8; ++e) {
          int k = part * 32 + uu * 8 + e;
          tmp[e] = (v[uu * 2 + (e >> 2)][e & 3] - mean) * rstd * gz[k] + bz[k];
        }
        int byte = (row * 256 + part * 64 + uu * 16) ^ ((row & 7) << 4);
        *reinterpret_cast<bf16x8*>(zns + byte) = pack8(tmp);
      }
    }
    __syncthreads();

    // MFMA: [128 j] x [16 h] x K=128
    bf16x8 av[2][4];
#pragma unroll
    for (int mf = 0; mf < 2; ++mf)
#pragma unroll
      for (int kf = 0; kf < 4; ++kf) {
        int row = wid * 32 + mf * 16 + r16;
        int byte = (row * 256 + (kf * 4 + kg) * 16) ^ ((row & 7) << 4);
        av[mf][kf] = *reinterpret_cast<const bf16x8*>(zns + byte);
      }
    f32x4 acc[2];
    acc[0] = (f32x4){0.f, 0.f, 0.f, 0.f}; acc[1] = acc[0];
#pragma unroll
    for (int mf = 0; mf < 2; ++mf)
#pragma unroll
      for (int kf = 0; kf < 4; ++kf)
        acc[mf] = __builtin_amdgcn_mfma_f32_16x16x32_bf16(av[mf][kf], bw[kf], acc[mf], 0, 0, 0);
    if (r16 < 8) {
#pragma unroll
      for (int mf = 0; mf < 2; ++mf)
#pragma unroll
        for (int r = 0; r < 4; ++r)
          bbl[r16][j0 + wid * 32 + mf * 16 + kg * 4 + r] = acc[mf][r];
    }
    __syncthreads();   // zns reused next jc; bbl complete at end
  }

  // softmax over j=512 per head; wave handles h = wid*2, wid*2+1
  f32x4 zm0 = *reinterpret_cast<const f32x4*>(z_mask + (size_t)i * 512 + lane * 8);
  f32x4 zm1 = *reinterpret_cast<const f32x4*>(z_mask + (size_t)i * 512 + lane * 8 + 4);
  float mbias[8];
#pragma unroll
  for (int e = 0; e < 4; ++e) { mbias[e] = 1e8f * (zm0[e] - 1.f); mbias[4 + e] = 1e8f * (zm1[e] - 1.f); }
#pragma unroll
  for (int hh = 0; hh < 2; ++hh) {
    const int h = wid * 2 + hh;
    f32x4 a = *reinterpret_cast<const f32x4*>(&bbl[h][lane * 8]);
    f32x4 b = *reinterpret_cast<const f32x4*>(&bbl[h][lane * 8 + 4]);
    float vals[8];
#pragma unroll
    for (int e = 0; e < 4; ++e) { vals[e] = a[e] + mbias[e]; vals[4 + e] = b[e] + mbias[4 + e]; }
    float mx = vals[0];
#pragma unroll
    for (int e = 1; e < 8; ++e) mx = fmaxf(mx, vals[e]);
#pragma unroll
    for (int msk = 1; msk < 64; msk <<= 1) mx = fmaxf(mx, __shfl_xor(mx, msk));
    float sum = 0.f;
#pragma unroll
    for (int e = 0; e < 8; ++e) { vals[e] = __expf(vals[e] - mx); sum += vals[e]; }
#pragma unroll
    for (int msk = 1; msk < 64; msk <<= 1) sum += __shfl_xor(sum, msk);
    float inv = 1.f / sum;
    bf16x8 o;
#pragma unroll
    for (int e = 0; e < 8; ++e) o[e] = (short)f2bf(vals[e] * inv);
    *reinterpret_cast<bf16x8*>(wbuf + ((size_t)h * 512 + i) * 512 + lane * 8) = o;
  }
}

// ---------------------------------------------------------------- k2
// grid (4, 256): (j-chunk, s). block 512 = 8 waves.
__global__ __launch_bounds__(512) void k2_vg(
    const float* __restrict__ m, const float* __restrict__ msa_mask,
    const float* __restrict__ gmp, const float* __restrict__ bmp,
    const u16* __restrict__ Wvg, u16* __restrict__ vT, u16* __restrict__ gbuf)
{
  const int jt = blockIdx.x, s = blockIdx.y;
  const int j0 = jt * 128;
  const int t = threadIdx.x, lane = t & 63, wid = t >> 6;
  const int r16 = lane & 15, kg = lane >> 4;
  __shared__ char smem[65536];   // [0,16K): LN tile bt; later: g transpose T[128 j][512B]
  __shared__ float maskl[128], gk[64], bk[64];
  if (t < 64) gk[t] = gmp[t];
  else if (t < 128) bk[t - 64] = bmp[t - 64];
  if (t < 128) maskl[t] = msa_mask[(size_t)s * 512 + j0 + t];
  __syncthreads();

  // LayerNorm: 4 threads per 64-f32 row, 128 rows
  {
    const int row = t >> 2, part = t & 3;
    const float* mr = m + ((size_t)s * 512 + j0 + row) * 64 + part * 16;
    f32x4 v[4];
    float sm = 0.f, sq = 0.f;
#pragma unroll
    for (int q = 0; q < 4; ++q) {
      v[q] = *reinterpret_cast<const f32x4*>(mr + 4 * q);
#pragma unroll
      for (int e = 0; e < 4; ++e) { sm += v[q][e]; sq += v[q][e] * v[q][e]; }
    }
    sm += __shfl_xor(sm, 1); sm += __shfl_xor(sm, 2);
    sq += __shfl_xor(sq, 1); sq += __shfl_xor(sq, 2);
    float mean = sm * (1.f / 64.f);
    float rstd = rsqrtf(sq * (1.f / 64.f) - mean * mean + 1e-5f);
#pragma unroll
    for (int uu = 0; uu < 2; ++uu) {
      float tmp[8];
#pragma unroll
      for (int e = 0; e < 8; ++e) {
        int k = part * 16 + uu * 8 + e;
        tmp[e] = (v[uu * 2 + (e >> 2)][e & 3] - mean) * rstd * gk[k] + bk[k];
      }
      int byte = (row * 128 + part * 32 + uu * 16) ^ ((row & 7) << 4);
      *reinterpret_cast<bf16x8*>(smem + byte) = pack8(tmp);
    }
  }
  __syncthreads();

  const int jh = wid & 1, hcq0 = wid >> 1;
  bf16x8 av[4][2];
#pragma unroll
  for (int mf = 0; mf < 4; ++mf)
#pragma unroll
    for (int kf = 0; kf < 2; ++kf) {
      int row = jh * 64 + mf * 16 + r16;
      int byte = (row * 128 + (kf * 4 + kg) * 16) ^ ((row & 7) << 4);
      av[mf][kf] = *reinterpret_cast<const bf16x8*>(smem + byte);
    }
  __syncthreads();   // LN tile reads done; smem free for g transpose

  // ---- rep0: v (W_v rows hcq0*64..), mask, DIRECT 8B stores
  {
    bf16x8 bv[4][2];
#pragma unroll
    for (int nf = 0; nf < 4; ++nf)
#pragma unroll
      for (int kf = 0; kf < 2; ++kf)
        bv[nf][kf] = *reinterpret_cast<const bf16x8*>(
            Wvg + (hcq0 * 64 + nf * 16 + r16) * 64 + kf * 32 + kg * 8);
    f32x4 acc[4][4];
#pragma unroll
    for (int mf = 0; mf < 4; ++mf)
#pragma unroll
      for (int nf = 0; nf < 4; ++nf) acc[mf][nf] = (f32x4){0.f, 0.f, 0.f, 0.f};
#pragma unroll
    for (int mf = 0; mf < 4; ++mf)
#pragma unroll
      for (int nf = 0; nf < 4; ++nf)
#pragma unroll
        for (int kf = 0; kf < 2; ++kf)
          acc[mf][nf] = __builtin_amdgcn_mfma_f32_16x16x32_bf16(av[mf][kf], bv[nf][kf], acc[mf][nf], 0, 0, 0);
#pragma unroll
    for (int mf = 0; mf < 4; ++mf) {
      const int jb = jh * 64 + mf * 16 + kg * 4;
      const float m0 = maskl[jb], m1 = maskl[jb + 1], m2 = maskl[jb + 2], m3 = maskl[jb + 3];
#pragma unroll
      for (int nf = 0; nf < 4; ++nf) {
        const int hc = hcq0 * 64 + nf * 16 + r16;
        const int h = hc >> 5, c = hc & 31;
        u32 lo = (u32)f2bf(acc[mf][nf][0] * m0) | ((u32)f2bf(acc[mf][nf][1] * m1) << 16);
        u32 hi = (u32)f2bf(acc[mf][nf][2] * m2) | ((u32)f2bf(acc[mf][nf][3] * m3) << 16);
        uint2 pk; pk.x = lo; pk.y = hi;
        *reinterpret_cast<uint2*>(vT + (((size_t)h * 8192 + s * 32 + c) * 512 + j0 + jb)) = pk;
      }
    }
  }

  // ---- rep1: g (W_g rows 256+..), sigmoid, transpose via LDS T[j][hc]
  {
    bf16x8 bv[4][2];
#pragma unroll
    for (int nf = 0; nf < 4; ++nf)
#pragma unroll
      for (int kf = 0; kf < 2; ++kf)
        bv[nf][kf] = *reinterpret_cast<const bf16x8*>(
            Wvg + ((hcq0 + 4) * 64 + nf * 16 + r16) * 64 + kf * 32 + kg * 8);
    f32x4 acc[4][4];
#pragma unroll
    for (int mf = 0; mf < 4; ++mf)
#pragma unroll
      for (int nf = 0; nf < 4; ++nf) acc[mf][nf] = (f32x4){0.f, 0.f, 0.f, 0.f};
#pragma unroll
    for (int mf = 0; mf < 4; ++mf)
#pragma unroll
      for (int nf = 0; nf < 4; ++nf)
#pragma unroll
        for (int kf = 0; kf < 2; ++kf)
          acc[mf][nf] = __builtin_amdgcn_mfma_f32_16x16x32_bf16(av[mf][kf], bv[nf][kf], acc[mf][nf], 0, 0, 0);
#pragma unroll
    for (int mf = 0; mf < 4; ++mf)
#pragma unroll
      for (int nf = 0; nf < 4; ++nf)
#pragma unroll
        for (int r = 0; r < 4; ++r) {
          int j = jh * 64 + mf * 16 + kg * 4 + r;
          int hc = hcq0 * 64 + nf * 16 + r16;
          float val = 1.f / (1.f + __expf(-acc[mf][nf][r]));
          int byte = (j * 512 + hc * 2) ^ ((j & 7) << 4);
          *reinterpret_cast<u16*>(smem + byte) = f2bf(val);
        }
  }
  __syncthreads();
  // block-contiguous 64 KB gbuf store: rows (s, j0+j) of 512B
#pragma unroll
  for (int it = 0; it < 8; ++it) {
    int u = it * 512 + t;
    int j = u >> 5, sub = u & 31;
    int byte = (j * 512 + sub * 16) ^ ((j & 7) << 4);
    bf16x8 rv = *reinterpret_cast<const bf16x8*>(smem + byte);
    *reinterpret_cast<bf16x8*>(gbuf + (((size_t)s * 512 + j0 + j) * 256 + sub * 8)) = rv;
  }
}

// ---------------------------------------------------------------- k3
// flat grid 2048, XCD-swizzled: h = id&7 (one head per XCD), mt innermost.
// block 256 = 4 waves (2x2). 128x128 tile, BK=64, swizzled LDS.
__global__ __launch_bounds__(256) void k3_einsum(
    const u16* __restrict__ wbuf, const u16* __restrict__ vT, u16* __restrict__ O2)
{
  const int id = blockIdx.x;
  const int h = id & 7, pos = id >> 3;
  const int nt = pos >> 2, mt = pos & 3;
  const int t = threadIdx.x, lane = t & 63, wid = t >> 6;
  const int Mbase = mt * 128, Nbase = nt * 128;
  __shared__ char smem[32768];     // at[128][128B] swz | btl[128][128B] swz ; epilogue Tep
  const u16* Ag = wbuf + (size_t)h * 262144;
  const u16* Bg = vT + (size_t)h * 4194304;
  const int wr = wid >> 1, wc = wid & 1;
  const int r16 = lane & 15, kg = lane >> 4;
  const int lrow = lane >> 3, lslot = lane & 7;
  f32x4 acc[4][4];
#pragma unroll
  for (int a = 0; a < 4; ++a)
#pragma unroll
    for (int b = 0; b < 4; ++b) acc[a][b] = (f32x4){0.f, 0.f, 0.f, 0.f};

  for (int kt = 0; kt < 8; ++kt) {
    const int k0 = kt * 64;
#pragma unroll
    for (int q = 0; q < 4; ++q) {
      const int rb = wid * 32 + q * 8;
      const int pr = rb + lrow;
      const int su = (lslot ^ (pr & 7)) * 8;   // pre-swizzled source column
      GLD_LDS16(Ag + (size_t)(Mbase + pr) * 512 + k0 + su, (u16*)smem + rb * 64);
      GLD_LDS16(Bg + (size_t)(Nbase + pr) * 512 + k0 + su, (u16*)(smem + 16384) + rb * 64);
    }
    __syncthreads();
    bf16x8 av[4][2], bv[4][2];
#pragma unroll
    for (int mf = 0; mf < 4; ++mf)
#pragma unroll
      for (int kf = 0; kf < 2; ++kf) {
        int rowA = wr * 64 + mf * 16 + r16;
        int byteA = (rowA * 128 + (kf * 4 + kg) * 16) ^ ((rowA & 7) << 4);
        av[mf][kf] = *reinterpret_cast<const bf16x8*>(smem + byteA);
        int rowB = wc * 64 + mf * 16 + r16;
        int byteB = (rowB * 128 + (kf * 4 + kg) * 16) ^ ((rowB & 7) << 4);
        bv[mf][kf] = *reinterpret_cast<const bf16x8*>(smem + 16384 + byteB);
      }
#pragma unroll
    for (int mf = 0; mf < 4; ++mf)
#pragma unroll
      for (int nf = 0; nf < 4; ++nf)
#pragma unroll
        for (int kf = 0; kf < 2; ++kf)
          acc[mf][nf] = __builtin_amdgcn_mfma_f32_16x16x32_bf16(av[mf][kf], bv[nf][kf], acc[mf][nf], 0, 0, 0);
    __syncthreads();
  }

  // epilogue: acc -> bf16 Tep[i 128][sc 128] -> coalesced O2[i][s][hc]
  u16* Tep = (u16*)smem;
#pragma unroll
  for (int mf = 0; mf < 4; ++mf)
#pragma unroll
    for (int nf = 0; nf < 4; ++nf)
#pragma unroll
      for (int r = 0; r < 4; ++r) {
        int il = wr * 64 + mf * 16 + kg * 4 + r;
        int sc = wc * 64 + nf * 16 + r16;
        Tep[il * 128 + sc] = f2bf(acc[mf][nf][r]);
      }
  __syncthreads();
#pragma unroll
  for (int it = 0; it < 8; ++it) {
    int u = it * 256 + t;
    int il = u >> 4, sub = u & 15;
    bf16x8 rv = *reinterpret_cast<const bf16x8*>(Tep + il * 128 + sub * 8);
    int scg = Nbase + sub * 8;
    int sI = scg >> 5, c = scg & 31;
    *reinterpret_cast<bf16x8*>(
        O2 + (((size_t)(Mbase + il) * 256 + sI) * 256 + h * 32 + c)) = rv;
  }
}

// ---------------------------------------------------------------- k4
// grid (4, 512): (s-tile, i). block 256 = 4 waves. M=64(s) N=64(cm) K=256(hc).
__global__ __launch_bounds__(256) void k4_out(
    const u16* __restrict__ O2, const u16* __restrict__ gbuf,
    const u16* __restrict__ Wo, float* __restrict__ out)
{
  const int st = blockIdx.x, i = blockIdx.y;
  const int s0 = st * 64;
  const int t = threadIdx.x, lane = t & 63, wid = t >> 6;
  const int r16 = lane & 15, kg = lane >> 4;
  __shared__ u16 Al[64][264];
  __shared__ u16 Wl[64][264];
#pragma unroll
  for (int it = 0; it < 8; ++it) {
    int u = it * 256 + t, row = u >> 5, sub = u & 31;
    *reinterpret_cast<bf16x8*>(&Wl[row][sub * 8]) =
        *reinterpret_cast<const bf16x8*>(Wo + row * 256 + sub * 8);
  }
  {
    const int sl = t >> 2, hc0 = (t & 3) * 64;
    const u16* Op = O2 + ((size_t)i * 256 + s0 + sl) * 256 + hc0;
    const u16* gp = gbuf + ((size_t)(s0 + sl) * 512 + i) * 256 + hc0;
#pragma unroll
    for (int uu = 0; uu < 8; ++uu) {
      bf16x8 ov = *reinterpret_cast<const bf16x8*>(Op + uu * 8);
      bf16x8 gv = *reinterpret_cast<const bf16x8*>(gp + uu * 8);
      bf16x8 r;
#pragma unroll
      for (int e = 0; e < 8; ++e) r[e] = (short)f2bf(bf2f((u16)ov[e]) * bf2f((u16)gv[e]));
      *reinterpret_cast<bf16x8*>(&Al[sl][hc0 + uu * 8]) = r;
    }
  }
  __syncthreads();

  f32x4 acc[4];
#pragma unroll
  for (int nf = 0; nf < 4; ++nf) acc[nf] = (f32x4){0.f, 0.f, 0.f, 0.f};
#pragma unroll
  for (int kf = 0; kf < 8; ++kf) {
    bf16x8 a = *reinterpret_cast<const bf16x8*>(&Al[wid * 16 + r16][kf * 32 + kg * 8]);
#pragma unroll
    for (int nf = 0; nf < 4; ++nf) {
      bf16x8 b = *reinterpret_cast<const bf16x8*>(&Wl[nf * 16 + r16][kf * 32 + kg * 8]);
      acc[nf] = __builtin_amdgcn_mfma_f32_16x16x32_bf16(a, b, acc[nf], 0, 0, 0);
    }
  }
  __syncthreads();
  // bounce out-tile through LDS (reuse Al region) -> 256B row stores
  float* Ot = (float*)&Al[0][0];   // [64][68]
#pragma unroll
  for (int nf = 0; nf < 4; ++nf)
#pragma unroll
    for (int r = 0; r < 4; ++r)
      Ot[(wid * 16 + kg * 4 + r) * 68 + nf * 16 + r16] = acc[nf][r];
  __syncthreads();
#pragma unroll
  for (int it = 0; it < 4; ++it) {
    int u = it * 256 + t;
    int row = u >> 4, unit = u & 15;
    f32x4 rv = *reinterpret_cast<const f32x4*>(Ot + row * 68 + unit * 4);
    *reinterpret_cast<f32x4*>(out + (((size_t)(s0 + row) * 512 + i) * 64 + unit * 4)) = rv;
  }
}

// ---------------------------------------------------------------- launcher
extern "C" void kernel_launch(void* const* d_in, const int* in_sizes, int n_in,
                              void* d_out, int out_size, void* d_ws, size_t ws_size,
                              hipStream_t stream) {
  const float* m        = (const float*)d_in[0];
  const float* z        = (const float*)d_in[1];
  const float* msa_mask = (const float*)d_in[2];
  const float* z_mask   = (const float*)d_in[3];
  const float* ln_m_g   = (const float*)d_in[4];
  const float* ln_m_b   = (const float*)d_in[5];
  const float* W_v      = (const float*)d_in[6];
  const float* W_g      = (const float*)d_in[7];
  const float* ln_z_g   = (const float*)d_in[8];
  const float* ln_z_b   = (const float*)d_in[9];
  const float* W_b      = (const float*)d_in[10];
  const float* W_o      = (const float*)d_in[11];
  float* out = (float*)d_out;

  char* ws = (char*)d_ws;
  u16*   Wvg  = (u16*)(ws);                 //  64 KiB [512][64]
  u16*   Wo   = (u16*)(ws + 65536);         //  32 KiB [64][256]
  u16*   Wb   = (u16*)(ws + 98304);         //   4 KiB [16][128]
  u16*   wbuf = (u16*)  (ws + (1u  << 20)); //   4 MiB [8][512][512]
  u16*   vT   = (u16*)  (ws + (8u  << 20)); //  64 MiB [8][8192][512]
  u16*   gbuf = (u16*)  (ws + (72u << 20)); //  64 MiB [256][512][256]
  u16*   O2   = (u16*)  (ws + (136u << 20));//  64 MiB [512][256][256]

  k0_convert<<<200, 256, 0, stream>>>(W_v, W_g, W_o, W_b, Wvg, Wo, Wb);
  k1_fused<<<512, 256, 0, stream>>>(z, z_mask, ln_z_g, ln_z_b, Wb, wbuf);
  k2_vg<<<dim3(4, 256), 512, 0, stream>>>(m, msa_mask, ln_m_g, ln_m_b, Wvg, vT, gbuf);
  k3_einsum<<<2048, 256, 0, stream>>>(wbuf, vT, O2);
  k4_out<<<dim3(4, 512), 256, 0, stream>>>(O2, gbuf, Wo, out);
}